// Round 11
// baseline (410.124 us; speedup 1.0000x reference)
//
#include <hip/hip_runtime.h>
#include <hip/hip_bf16.h>
#include <stdint.h>

#define S_LEN 2048
#define DM 1024
#define NH 16
#define HD 64

typedef __bf16 bf16x8 __attribute__((ext_vector_type(8)));
typedef float f32x4 __attribute__((ext_vector_type(4)));
typedef unsigned short u16x4 __attribute__((ext_vector_type(4)));

#if __has_builtin(__builtin_amdgcn_exp2f)
#define EXP2F(x) __builtin_amdgcn_exp2f(x)
#else
#define EXP2F(x) exp2f(x)
#endif

__device__ __forceinline__ unsigned short f2bf(float f){
  union { float f; uint32_t u; } v; v.f = f;
  uint32_t r = v.u + 0x7fffu + ((v.u >> 16) & 1u);
  return (unsigned short)(r >> 16);
}

__device__ __forceinline__ float bf2f(unsigned short u){
  union { uint32_t u; float f; } v; v.u = ((uint32_t)u) << 16;
  return v.f;
}

__device__ __forceinline__ void load_lds16(const void* g, void* l){
  __builtin_amdgcn_global_load_lds((const __attribute__((address_space(1))) void*)g,
                                   (__attribute__((address_space(3))) void*)l, 16, 0, 0);
}

__device__ __forceinline__ f32x4 mfma16(bf16x8 a, bf16x8 b, f32x4 c){
  return __builtin_amdgcn_mfma_f32_16x16x32_bf16(a, b, c, 0, 0, 0);
}

// rows are 64 bf16 = 128B; swizzle byte_off ^= ((row&7)<<4) to break the 128B-stride bank conflict
__device__ __forceinline__ bf16x8 lds_swz_read(const unsigned short* base, int row, int cb){
  int addr = (row << 7) + (cb ^ ((row & 7) << 4));
  return *reinterpret_cast<const bf16x8*>(reinterpret_cast<const char*>(base) + addr);
}

// ---------------- prep: f32 -> bf16 for x and the 4 weight matrices ----------------
__global__ void prep_kernel(const float* __restrict__ x,
                            const float* __restrict__ wq, const float* __restrict__ wk,
                            const float* __restrict__ wv, const float* __restrict__ wo,
                            unsigned short* __restrict__ ws_base){
  long idx = ((long)blockIdx.x * 256 + threadIdx.x) * 4;
  const float* s; unsigned short* d; long off;
  if (idx < (1L << 22)) { s = x; d = ws_base; off = idx; }
  else {
    long r = idx - (1L << 22);
    int wsel = (int)(r >> 20);
    off = r & ((1L << 20) - 1);
    s = wsel == 0 ? wq : wsel == 1 ? wk : wsel == 2 ? wv : wo;
    d = ws_base + (1L << 22) + ((long)wsel << 20);
  }
  float4 f = *reinterpret_cast<const float4*>(s + off);
  u16x4 o;
  o[0] = f2bf(f.x); o[1] = f2bf(f.y); o[2] = f2bf(f.z); o[3] = f2bf(f.w);
  *reinterpret_cast<u16x4*>(d + off) = o;
}

// ---------------- GEMM: C = A[M,1024] * B[N,1024]^T + bias ----------------
template<int MODE>
__global__ __launch_bounds__(256, 2)
void gemm_bt_kernel(const unsigned short* __restrict__ A,
                    const unsigned short* __restrict__ B0,
                    const unsigned short* __restrict__ B1,
                    const unsigned short* __restrict__ B2,
                    const float* __restrict__ bias0,
                    const float* __restrict__ bias1,
                    const float* __restrict__ bias2,
                    unsigned short* __restrict__ q_out,
                    unsigned short* __restrict__ k_out,
                    unsigned short* __restrict__ vt_out,
                    float* __restrict__ f_out)
{
  __shared__ unsigned short As[128 * 64];
  __shared__ unsigned short Bs[128 * 64];
  const int tid = threadIdx.x;
  const int lane = tid & 63;
  const int w = tid >> 6;
  const int wr = w >> 1, wc = w & 1;
  const int mBase = blockIdx.y * 128;
  int nb = blockIdx.x;
  const unsigned short* Bmat; const float* bias; int mat;
  if constexpr (MODE == 0) {
    mat = nb >> 3;
    nb &= 7;
    Bmat = mat == 0 ? B0 : (mat == 1 ? B1 : B2);
    bias = mat == 0 ? bias0 : (mat == 1 ? bias1 : bias2);
  } else { mat = 0; Bmat = B0; bias = bias0; }
  const int nBase = nb * 128;

  f32x4 acc[4][4] = {};
  const int srow = lane >> 3;
  const int ksrc = ((lane & 7) ^ srow) * 8;
  const unsigned short* ArowBase = A    + (size_t)(mBase + w * 32 + srow) * DM + ksrc;
  const unsigned short* BrowBase = Bmat + (size_t)(nBase + w * 32 + srow) * DM + ksrc;

  for (int kt = 0; kt < 16; ++kt) {
    #pragma unroll
    for (int i = 0; i < 4; ++i) {
      load_lds16(ArowBase + (size_t)(i * 8) * DM + kt * 64, &As[(w * 4 + i) * 512]);
      load_lds16(BrowBase + (size_t)(i * 8) * DM + kt * 64, &Bs[(w * 4 + i) * 512]);
    }
    __syncthreads();
    #pragma unroll
    for (int kk = 0; kk < 2; ++kk) {
      bf16x8 af[4], bfr[4];
      const int cb = kk * 64 + ((lane >> 4) << 4);
      #pragma unroll
      for (int m = 0; m < 4; ++m)
        af[m] = lds_swz_read(As, wr * 64 + m * 16 + (lane & 15), cb);
      #pragma unroll
      for (int n = 0; n < 4; ++n)
        bfr[n] = lds_swz_read(Bs, wc * 64 + n * 16 + (lane & 15), cb);
      #pragma unroll
      for (int m = 0; m < 4; ++m)
        #pragma unroll
        for (int n = 0; n < 4; ++n)
          acc[m][n] = mfma16(af[m], bfr[n], acc[m][n]);
    }
    __syncthreads();
  }

  #pragma unroll
  for (int m = 0; m < 4; ++m) {
    #pragma unroll
    for (int n = 0; n < 4; ++n) {
      const int col = nBase + wc * 64 + n * 16 + (lane & 15);
      const float bv = bias[col];
      const int row0 = mBase + wr * 64 + m * 16 + ((lane >> 4) << 2);
      if constexpr (MODE == 1) {
        #pragma unroll
        for (int j = 0; j < 4; ++j)
          f_out[(size_t)(row0 + j) * DM + col] = acc[m][n][j] + bv;
      } else {
        const int h = col >> 6, d = col & 63;
        if (mat < 2) {
          unsigned short* dst = (mat == 0) ? q_out : k_out;
          #pragma unroll
          for (int j = 0; j < 4; ++j) {
            const int row = row0 + j;
            const int b = row >> 11, s = row & 2047;
            dst[(((size_t)b * NH + h) * S_LEN + s) * HD + d] = f2bf(acc[m][n][j] + bv);
          }
        } else {
          const int b = row0 >> 11, s = row0 & 2047;
          u16x4 pk;
          #pragma unroll
          for (int j = 0; j < 4; ++j) pk[j] = f2bf(acc[m][n][j] + bv);
          *reinterpret_cast<u16x4*>(&vt_out[(((size_t)b * NH + h) * HD + d) * S_LEN + s]) = pk;
        }
      }
    }
  }
}

// ---------------- flash attention: SPLIT-K x2 + 24KB LDS for occupancy (TLP) ----------------
// r2/r5/r7/r9 all ~200us across 4 sync schemes -> not a scheduling problem; ~65% of wall
// is uncovered stall at 16 waves/CU. Fix: split K-range in 2 (2048 blocks), single-buffer
// K/V (24KB LDS -> 6 blocks/CU LDS-cap), waves_per_eu(5,8).
// r10 faulted: LOAD_RAW got kv0-double-counted offsets (OOB past rel_bias) and Mbuf was
// placed beyond the proven ws footprint. Fixed: LOAD_RAW takes LOCAL offsets (bp/mp
// pre-offset by kv0); partials/Mb/Lb reuse dead ws regions (xb, wqb) -- footprint 48MB.
// Counted-vmcnt single-buffer tile: entry has raw(t)=8 in flight;
//   BAR; stage K/V(t) [4]; vmcnt(4) retires raw(t); COMBINE; issue raw(t+1) [8];
//   vmcnt(8) retires stages (raw(t+1) stays in flight); BAR; QK+softmax+PV(t).

#define WAITV8 do { asm volatile("s_waitcnt vmcnt(8)" ::: "memory"); } while (0)
#define WAITV4 do { asm volatile("s_waitcnt vmcnt(4)" ::: "memory"); } while (0)
#define WAITV0 do { asm volatile("s_waitcnt vmcnt(0)" ::: "memory"); } while (0)
#define SB0    __builtin_amdgcn_sched_barrier(0)
#define BAR    __builtin_amdgcn_s_barrier()

// lB is LOCAL to this split (bp/mp already include kv0); lB in [0, 960]
#define LOAD_RAW(lB) do {                                                     \
    rb0 = *reinterpret_cast<const f32x4*>(bp + (lB) + g * 4);                 \
    rm0 = *reinterpret_cast<const f32x4*>(mp + (lB) + g * 4);                 \
    rb1 = *reinterpret_cast<const f32x4*>(bp + (lB) + 16 + g * 4);            \
    rm1 = *reinterpret_cast<const f32x4*>(mp + (lB) + 16 + g * 4);            \
    rb2 = *reinterpret_cast<const f32x4*>(bp + (lB) + 32 + g * 4);            \
    rm2 = *reinterpret_cast<const f32x4*>(mp + (lB) + 32 + g * 4);            \
    rb3 = *reinterpret_cast<const f32x4*>(bp + (lB) + 48 + g * 4);            \
    rm3 = *reinterpret_cast<const f32x4*>(mp + (lB) + 48 + g * 4);            \
  } while (0)

#define COMBINE do {                                                          \
    bm0 = (rb0 + rm0) * L2E; bm1 = (rb1 + rm1) * L2E;                         \
    bm2 = (rb2 + rm2) * L2E; bm3 = (rb3 + rm3) * L2E;                         \
  } while (0)

// kvB is GLOBAL (Kp/Vp do not include kv0)
#define STAGE_K(kvB) do {                                                                    \
    load_lds16(Kp + (size_t)((kvB) + w * 16 + srow) * HD + ksrc,     &Ks[(w * 2) * 512]);    \
    load_lds16(Kp + (size_t)((kvB) + w * 16 + 8 + srow) * HD + ksrc, &Ks[(w * 2 + 1) * 512]);\
  } while (0)

#define STAGE_V(kvB) do {                                                                    \
    load_lds16(Vp + (size_t)(w * 16 + srow) * S_LEN + (kvB) + ksrc,     &Vs[(w * 2) * 512]);    \
    load_lds16(Vp + (size_t)(w * 16 + 8 + srow) * S_LEN + (kvB) + ksrc, &Vs[(w * 2 + 1) * 512]);\
  } while (0)

#define BIAS_COL(SCN, BMN) do {                                               \
    SCN[0] = SCN[0] * SC + BMN[0];                                            \
    SCN[1] = SCN[1] * SC + BMN[1];                                            \
    SCN[2] = SCN[2] * SC + BMN[2];                                            \
    SCN[3] = SCN[3] * SC + BMN[3];                                            \
    mt_ = fmaxf(mt_, fmaxf(fmaxf(SCN[0], SCN[1]), fmaxf(SCN[2], SCN[3])));    \
  } while (0)

#define EXP_COL(SCN) do {                                                     \
    SCN[0] = EXP2F(SCN[0] - mn_); SCN[1] = EXP2F(SCN[1] - mn_);               \
    SCN[2] = EXP2F(SCN[2] - mn_); SCN[3] = EXP2F(SCN[3] - mn_);               \
  } while (0)

#define PWR_COL(NN, SCN) do {                                                 \
    u16x4 pk_;                                                                \
    pk_[0] = f2bf(SCN[0]); pk_[1] = f2bf(SCN[1]);                             \
    pk_[2] = f2bf(SCN[2]); pk_[3] = f2bf(SCN[3]);                             \
    const int colb_ = ((NN) * 16 + 4 * g) * 2;                                \
    *reinterpret_cast<u16x4*>(                                                \
        reinterpret_cast<char*>(Pw_) + (q << 7) + (colb_ ^ ((q & 7) << 4))) = pk_; \
  } while (0)

#define COMPUTE_TILE do {                                                     \
    f32x4 sc0_, sc1_, sc2_, sc3_;                                             \
    { bf16x8 a_ = lds_swz_read(Ks, 0 * 16 + q, cbq);                          \
      bf16x8 b_ = lds_swz_read(Ks, 0 * 16 + q, 64 + cbq);                     \
      f32x4 z_ = {}; z_ = mfma16(a_, qf0, z_); sc0_ = mfma16(b_, qf1, z_); }  \
    { bf16x8 a_ = lds_swz_read(Ks, 1 * 16 + q, cbq);                          \
      bf16x8 b_ = lds_swz_read(Ks, 1 * 16 + q, 64 + cbq);                     \
      f32x4 z_ = {}; z_ = mfma16(a_, qf0, z_); sc1_ = mfma16(b_, qf1, z_); }  \
    { bf16x8 a_ = lds_swz_read(Ks, 2 * 16 + q, cbq);                          \
      bf16x8 b_ = lds_swz_read(Ks, 2 * 16 + q, 64 + cbq);                     \
      f32x4 z_ = {}; z_ = mfma16(a_, qf0, z_); sc2_ = mfma16(b_, qf1, z_); }  \
    { bf16x8 a_ = lds_swz_read(Ks, 3 * 16 + q, cbq);                          \
      bf16x8 b_ = lds_swz_read(Ks, 3 * 16 + q, 64 + cbq);                     \
      f32x4 z_ = {}; z_ = mfma16(a_, qf0, z_); sc3_ = mfma16(b_, qf1, z_); }  \
    float mt_ = -3.0e38f;                                                     \
    BIAS_COL(sc0_, bm0); BIAS_COL(sc1_, bm1);                                 \
    BIAS_COL(sc2_, bm2); BIAS_COL(sc3_, bm3);                                 \
    mt_ = fmaxf(mt_, __shfl_xor(mt_, 16));                                    \
    mt_ = fmaxf(mt_, __shfl_xor(mt_, 32));                                    \
    const float mn_ = fmaxf(m_run, mt_);                                      \
    const float corr_ = EXP2F(m_run - mn_);                                   \
    m_run = mn_;                                                              \
    EXP_COL(sc0_); EXP_COL(sc1_); EXP_COL(sc2_); EXP_COL(sc3_);               \
    f32x4 ls4_ = sc0_ + sc1_ + sc2_ + sc3_;                                   \
    float ls_ = ls4_[0] + ls4_[1] + ls4_[2] + ls4_[3];                        \
    ls_ += __shfl_xor(ls_, 16);                                               \
    ls_ += __shfl_xor(ls_, 32);                                               \
    l_run = l_run * corr_ + ls_;                                              \
    acc0_ *= corr_; acc1_ *= corr_; acc2_ *= corr_; acc3_ *= corr_;           \
    PWR_COL(0, sc0_); PWR_COL(1, sc1_); PWR_COL(2, sc2_); PWR_COL(3, sc3_);   \
    bf16x8 pf0_ = lds_swz_read(Pw_, q, cbq);                                  \
    bf16x8 pf1_ = lds_swz_read(Pw_, q, 64 + cbq);                             \
    { bf16x8 a_ = lds_swz_read(Vs, 0 * 16 + q, cbq);                          \
      bf16x8 b_ = lds_swz_read(Vs, 0 * 16 + q, 64 + cbq);                     \
      acc0_ = mfma16(a_, pf0_, acc0_); acc0_ = mfma16(b_, pf1_, acc0_); }     \
    { bf16x8 a_ = lds_swz_read(Vs, 1 * 16 + q, cbq);                          \
      bf16x8 b_ = lds_swz_read(Vs, 1 * 16 + q, 64 + cbq);                     \
      acc1_ = mfma16(a_, pf0_, acc1_); acc1_ = mfma16(b_, pf1_, acc1_); }     \
    { bf16x8 a_ = lds_swz_read(Vs, 2 * 16 + q, cbq);                          \
      bf16x8 b_ = lds_swz_read(Vs, 2 * 16 + q, 64 + cbq);                     \
      acc2_ = mfma16(a_, pf0_, acc2_); acc2_ = mfma16(b_, pf1_, acc2_); }     \
    { bf16x8 a_ = lds_swz_read(Vs, 3 * 16 + q, cbq);                          \
      bf16x8 b_ = lds_swz_read(Vs, 3 * 16 + q, 64 + cbq);                     \
      acc3_ = mfma16(a_, pf0_, acc3_); acc3_ = mfma16(b_, pf1_, acc3_); }     \
  } while (0)

__global__ __launch_bounds__(256) __attribute__((amdgpu_waves_per_eu(5, 8)))
void attn_kernel(const unsigned short* __restrict__ Q,
                 const unsigned short* __restrict__ Kmat,
                 const unsigned short* __restrict__ Vt,
                 const float* __restrict__ rel_bias,
                 const float* __restrict__ mask,
                 unsigned short* __restrict__ ctxp0,
                 unsigned short* __restrict__ ctxp1,
                 float* __restrict__ Mbuf,
                 float* __restrict__ Lbuf)
{
  __shared__ unsigned short Ks[64 * 64];
  __shared__ unsigned short Vs[64 * 64];
  __shared__ unsigned short Ps[4][16 * 64];

  // XCD-chunked bijective remap: 2048 = 8 XCDs x 256; (s, b) fastest so blocks sharing
  // bias rows land on the same XCD.
  const int logical = (blockIdx.x & 7) * 256 + (blockIdx.x >> 3);
  const int s  = logical & 1;          // K-split
  const int b  = (logical >> 1) & 1;
  const int qt = (logical >> 2) & 31;
  const int h  = logical >> 7;

  const int lane = threadIdx.x & 63, w = threadIdx.x >> 6;
  const int q = lane & 15, g = lane >> 4;
  const int bh = b * NH + h;
  const int qRow = qt * 64 + w * 16;
  const int kv0 = s << 10;             // this split's k base (global elements)
  const unsigned short* Qp = Q + ((size_t)bh * S_LEN + qRow) * HD;
  bf16x8 qf0 = *reinterpret_cast<const bf16x8*>(Qp + (size_t)q * HD + g * 8);
  bf16x8 qf1 = *reinterpret_cast<const bf16x8*>(Qp + (size_t)q * HD + 32 + g * 8);

  const unsigned short* Kp = Kmat + (size_t)bh * S_LEN * HD;
  const unsigned short* Vp = Vt + (size_t)bh * HD * S_LEN;
  const float* bp = rel_bias + (size_t)h * S_LEN * S_LEN + (size_t)(qRow + q) * S_LEN + kv0;
  const float* mp = mask + (size_t)(qRow + q) * S_LEN + kv0;

  float m_run = -3.0e38f, l_run = 0.f;
  f32x4 acc0_ = {}, acc1_ = {}, acc2_ = {}, acc3_ = {};
  f32x4 rb0, rb1, rb2, rb3, rm0, rm1, rm2, rm3;
  f32x4 bm0, bm1, bm2, bm3;

  const float SC  = 0.125f * 1.44269504089f;  // head scale * log2(e)
  const float L2E = 1.44269504089f;

  const int srow = lane >> 3;
  const int ksrc = ((lane & 7) ^ srow) * 8;   // pre-swizzled global k-offset
  const int cbq = g << 4;
  unsigned short* Pw_ = Ps[w];

  // prologue: raw(0) in flight (8) -- loop entry invariant
  LOAD_RAW(0);
  SB0;

  for (int t = 0; t < 15; ++t) {
    const int kvB = kv0 + t * 64;      // global
    BAR;                               // all waves done reading Ks/Vs of t-1
    STAGE_K(kvB); STAGE_V(kvB);        // in-flight: raw(t)8 + stage4
    SB0;
    WAITV4; SB0;                       // retire raw(t); stages remain
    COMBINE;                           // bm <- raw(t)
    LOAD_RAW((t + 1) * 64);            // raw(t+1), LOCAL offset
    SB0;
    WAITV8; SB0;                       // retire stages; raw(t+1) stays in flight
    BAR;                               // stages visible to all waves
    COMPUTE_TILE;
  }
  // tail t = 15
  {
    const int kvB = kv0 + 15 * 64;
    BAR;
    STAGE_K(kvB); STAGE_V(kvB);
    SB0;
    WAITV4; SB0;
    COMBINE;
    WAITV0; SB0;
    BAR;
    COMPUTE_TILE;
  }

  // epilogue: normalize, redistribute through per-wave LDS, write split partial
  const float inv = 1.0f / l_run;
  acc0_ *= inv; acc1_ *= inv; acc2_ *= inv; acc3_ *= inv;
  PWR_COL(0, acc0_); PWR_COL(1, acc1_); PWR_COL(2, acc2_); PWR_COL(3, acc3_);
  bf16x8 c0 = lds_swz_read(Pw_, q, g << 4);
  bf16x8 c1 = lds_swz_read(Pw_, q, 64 + (g << 4));
  unsigned short* cp = (s ? ctxp1 : ctxp0) +
                       ((size_t)(b * S_LEN + qRow + q)) * DM + h * HD;
  *reinterpret_cast<bf16x8*>(cp + 8 * g) = c0;
  *reinterpret_cast<bf16x8*>(cp + 32 + 8 * g) = c1;
  if (g == 0) {
    const int mlIdx = (s << 16) + (bh << 11) + qRow + q;
    Mbuf[mlIdx] = m_run;
    Lbuf[mlIdx] = l_run;
  }
}

// ---------------- merge: combine the two K-split partials ----------------
// reads ctxp0[e] (== ctx region) and ctxp1[e], writes ctx[e] in place (same-address
// read-then-write per thread; no cross-element deps).
__global__ void merge_kernel(const unsigned short* __restrict__ ctxp0,
                             const unsigned short* __restrict__ ctxp1,
                             const float* __restrict__ Mbuf,
                             const float* __restrict__ Lbuf,
                             unsigned short* __restrict__ ctx){
  const long e = ((long)blockIdx.x * 256 + threadIdx.x) * 4;  // elem in [B*S*DM = 4M]
  const int b = (int)(e >> 21);
  const int srow = (int)((e >> 10) & 2047);
  const int d = (int)(e & 1023);
  const int h = d >> 6;
  const int idx = ((b * NH + h) << 11) + srow;
  const float m0 = Mbuf[idx],  m1 = Mbuf[(1 << 16) + idx];
  const float l0 = Lbuf[idx],  l1 = Lbuf[(1 << 16) + idx];
  const float mm = fmaxf(m0, m1);
  const float w0 = EXP2F(m0 - mm) * l0;
  const float w1 = EXP2F(m1 - mm) * l1;
  const float inv = 1.0f / (w0 + w1);
  u16x4 c0 = *reinterpret_cast<const u16x4*>(ctxp0 + e);
  u16x4 c1 = *reinterpret_cast<const u16x4*>(ctxp1 + e);
  u16x4 o;
  #pragma unroll
  for (int j = 0; j < 4; ++j)
    o[j] = f2bf((bf2f(c0[j]) * w0 + bf2f(c1[j]) * w1) * inv);
  *reinterpret_cast<u16x4*>(ctx + e) = o;
}

extern "C" void kernel_launch(void* const* d_in, const int* in_sizes, int n_in,
                              void* d_out, int out_size, void* d_ws, size_t ws_size,
                              hipStream_t stream) {
  (void)in_sizes; (void)n_in; (void)out_size; (void)ws_size;
  const float* x  = (const float*)d_in[0];
  const float* rb = (const float*)d_in[1];
  const float* mk = (const float*)d_in[2];
  const float* Wq = (const float*)d_in[3];
  const float* bq = (const float*)d_in[4];
  const float* Wk = (const float*)d_in[5];
  const float* bk = (const float*)d_in[6];
  const float* Wv = (const float*)d_in[7];
  const float* bv = (const float*)d_in[8];
  const float* Wo = (const float*)d_in[9];
  const float* bo = (const float*)d_in[10];
  float* out = (float*)d_out;

  // ws layout (unsigned short elems), 24M total = 48MB (same as passing rounds):
  //  [0,4M)    xb      (QKV GEMM input; DEAD after gemm<0> -> reused as split-1 partial)
  //  [4M,5M)   wqb     (DEAD after gemm<0> -> reused as Mbuf/Lbuf, 1.5MB of 2MB)
  //  [5M,6M)   wkb     [6M,7M) wvb    [7M,8M) wob (wob live until gemm<1>)
  //  [8M,12M)  Qw   [12M,16M) Kw   [16M,20M) Vtw
  //  [20M,24M) ctx  (split-0 partial, then merged in place)
  unsigned short* ws  = (unsigned short*)d_ws;
  unsigned short* xb  = ws;
  unsigned short* wqb = ws + (1L << 22);
  unsigned short* wkb = wqb + (1L << 20);
  unsigned short* wvb = wkb + (1L << 20);
  unsigned short* wob = wvb + (1L << 20);
  unsigned short* Qw  = wob + (1L << 20);
  unsigned short* Kw  = Qw + (1L << 22);
  unsigned short* Vtw = Kw + (1L << 22);
  unsigned short* ctx = Vtw + (1L << 22);
  unsigned short* ctxp1 = xb;                 // split-1 partial reuses xb
  float* Mb = (float*)wqb;                    // 2^17 f32 = 512KB
  float* Lb = (float*)(wqb + (1L << 19));     // next 512KB, still inside wqb's 2MB

  prep_kernel<<<8192, 256, 0, stream>>>(x, Wq, Wk, Wv, Wo, ws);
  gemm_bt_kernel<0><<<dim3(24, 32), 256, 0, stream>>>(
      xb, wqb, wkb, wvb, bq, bk, bv, Qw, Kw, Vtw, nullptr);
  attn_kernel<<<2048, 256, 0, stream>>>(Qw, Kw, Vtw, rb, mk, ctx, ctxp1, Mb, Lb);
  merge_kernel<<<4096, 256, 0, stream>>>(ctx, ctxp1, Mb, Lb, ctx);
  gemm_bt_kernel<1><<<dim3(8, 32), 256, 0, stream>>>(
      ctx, wob, nullptr, nullptr, bo, nullptr, nullptr, nullptr, nullptr, nullptr, out);
}

// Round 12
// 225.358 us; speedup vs baseline: 1.8199x; 1.8199x over previous
//
#include <hip/hip_runtime.h>
#include <hip/hip_bf16.h>
#include <stdint.h>

#define S_LEN 2048
#define DM 1024
#define NH 16
#define HD 64

typedef __bf16 bf16x8 __attribute__((ext_vector_type(8)));
typedef float f32x4 __attribute__((ext_vector_type(4)));
typedef unsigned short u16x4 __attribute__((ext_vector_type(4)));

#if __has_builtin(__builtin_amdgcn_exp2f)
#define EXP2F(x) __builtin_amdgcn_exp2f(x)
#else
#define EXP2F(x) exp2f(x)
#endif

__device__ __forceinline__ unsigned short f2bf(float f){
  union { float f; uint32_t u; } v; v.f = f;
  uint32_t r = v.u + 0x7fffu + ((v.u >> 16) & 1u);
  return (unsigned short)(r >> 16);
}

__device__ __forceinline__ float bf2f(unsigned short u){
  union { uint32_t u; float f; } v; v.u = ((uint32_t)u) << 16;
  return v.f;
}

__device__ __forceinline__ void load_lds16(const void* g, void* l){
  __builtin_amdgcn_global_load_lds((const __attribute__((address_space(1))) void*)g,
                                   (__attribute__((address_space(3))) void*)l, 16, 0, 0);
}

__device__ __forceinline__ f32x4 mfma16(bf16x8 a, bf16x8 b, f32x4 c){
  return __builtin_amdgcn_mfma_f32_16x16x32_bf16(a, b, c, 0, 0, 0);
}

// rows are 64 bf16 = 128B; swizzle byte_off ^= ((row&7)<<4) to break the 128B-stride bank conflict
__device__ __forceinline__ bf16x8 lds_swz_read(const unsigned short* base, int row, int cb){
  int addr = (row << 7) + (cb ^ ((row & 7) << 4));
  return *reinterpret_cast<const bf16x8*>(reinterpret_cast<const char*>(base) + addr);
}

// ---------------- prep: f32 -> bf16 for x and the 4 weight matrices ----------------
__global__ void prep_kernel(const float* __restrict__ x,
                            const float* __restrict__ wq, const float* __restrict__ wk,
                            const float* __restrict__ wv, const float* __restrict__ wo,
                            unsigned short* __restrict__ ws_base){
  long idx = ((long)blockIdx.x * 256 + threadIdx.x) * 4;
  const float* s; unsigned short* d; long off;
  if (idx < (1L << 22)) { s = x; d = ws_base; off = idx; }
  else {
    long r = idx - (1L << 22);
    int wsel = (int)(r >> 20);
    off = r & ((1L << 20) - 1);
    s = wsel == 0 ? wq : wsel == 1 ? wk : wsel == 2 ? wv : wo;
    d = ws_base + (1L << 22) + ((long)wsel << 20);
  }
  float4 f = *reinterpret_cast<const float4*>(s + off);
  u16x4 o;
  o[0] = f2bf(f.x); o[1] = f2bf(f.y); o[2] = f2bf(f.z); o[3] = f2bf(f.w);
  *reinterpret_cast<u16x4*>(d + off) = o;
}

// ---------------- GEMM: C = A[M,1024] * B[N,1024]^T + bias ----------------
template<int MODE>
__global__ __launch_bounds__(256, 2)
void gemm_bt_kernel(const unsigned short* __restrict__ A,
                    const unsigned short* __restrict__ B0,
                    const unsigned short* __restrict__ B1,
                    const unsigned short* __restrict__ B2,
                    const float* __restrict__ bias0,
                    const float* __restrict__ bias1,
                    const float* __restrict__ bias2,
                    unsigned short* __restrict__ q_out,
                    unsigned short* __restrict__ k_out,
                    unsigned short* __restrict__ vt_out,
                    float* __restrict__ f_out)
{
  __shared__ unsigned short As[128 * 64];
  __shared__ unsigned short Bs[128 * 64];
  const int tid = threadIdx.x;
  const int lane = tid & 63;
  const int w = tid >> 6;
  const int wr = w >> 1, wc = w & 1;
  const int mBase = blockIdx.y * 128;
  int nb = blockIdx.x;
  const unsigned short* Bmat; const float* bias; int mat;
  if constexpr (MODE == 0) {
    mat = nb >> 3;
    nb &= 7;
    Bmat = mat == 0 ? B0 : (mat == 1 ? B1 : B2);
    bias = mat == 0 ? bias0 : (mat == 1 ? bias1 : bias2);
  } else { mat = 0; Bmat = B0; bias = bias0; }
  const int nBase = nb * 128;

  f32x4 acc[4][4] = {};
  const int srow = lane >> 3;
  const int ksrc = ((lane & 7) ^ srow) * 8;
  const unsigned short* ArowBase = A    + (size_t)(mBase + w * 32 + srow) * DM + ksrc;
  const unsigned short* BrowBase = Bmat + (size_t)(nBase + w * 32 + srow) * DM + ksrc;

  for (int kt = 0; kt < 16; ++kt) {
    #pragma unroll
    for (int i = 0; i < 4; ++i) {
      load_lds16(ArowBase + (size_t)(i * 8) * DM + kt * 64, &As[(w * 4 + i) * 512]);
      load_lds16(BrowBase + (size_t)(i * 8) * DM + kt * 64, &Bs[(w * 4 + i) * 512]);
    }
    __syncthreads();
    #pragma unroll
    for (int kk = 0; kk < 2; ++kk) {
      bf16x8 af[4], bfr[4];
      const int cb = kk * 64 + ((lane >> 4) << 4);
      #pragma unroll
      for (int m = 0; m < 4; ++m)
        af[m] = lds_swz_read(As, wr * 64 + m * 16 + (lane & 15), cb);
      #pragma unroll
      for (int n = 0; n < 4; ++n)
        bfr[n] = lds_swz_read(Bs, wc * 64 + n * 16 + (lane & 15), cb);
      #pragma unroll
      for (int m = 0; m < 4; ++m)
        #pragma unroll
        for (int n = 0; n < 4; ++n)
          acc[m][n] = mfma16(af[m], bfr[n], acc[m][n]);
    }
    __syncthreads();
  }

  #pragma unroll
  for (int m = 0; m < 4; ++m) {
    #pragma unroll
    for (int n = 0; n < 4; ++n) {
      const int col = nBase + wc * 64 + n * 16 + (lane & 15);
      const float bv = bias[col];
      const int row0 = mBase + wr * 64 + m * 16 + ((lane >> 4) << 2);
      if constexpr (MODE == 1) {
        #pragma unroll
        for (int j = 0; j < 4; ++j)
          f_out[(size_t)(row0 + j) * DM + col] = acc[m][n][j] + bv;
      } else {
        const int h = col >> 6, d = col & 63;
        if (mat < 2) {
          unsigned short* dst = (mat == 0) ? q_out : k_out;
          #pragma unroll
          for (int j = 0; j < 4; ++j) {
            const int row = row0 + j;
            const int b = row >> 11, s = row & 2047;
            dst[(((size_t)b * NH + h) * S_LEN + s) * HD + d] = f2bf(acc[m][n][j] + bv);
          }
        } else {
          const int b = row0 >> 11, s = row0 & 2047;
          u16x4 pk;
          #pragma unroll
          for (int j = 0; j < 4; ++j) pk[j] = f2bf(acc[m][n][j] + bv);
          *reinterpret_cast<u16x4*>(&vt_out[(((size_t)b * NH + h) * HD + d) * S_LEN + s]) = pk;
        }
      }
    }
  }
}

// ---------------- flash attention: SPLIT-K x2 + 24KB LDS, spill-fixed occupancy ----------------
// r11 proved the occupancy thesis (occ 27->50 drove hbm 1.45->2.9 TB/s) but waves_per_eu(5,8)
// made the allocator target 8 waves/EU (64-reg budget) -> VGPR 48 + 326MB spill traffic.
// Fix: waves_per_eu(4,5) -> budget ~102 regs >= the ~100 (84 VGPR + 16 acc) this kernel
// needs -> no spill, 5 blocks/CU = 20 waves/CU. Schedule identical to r11 (correctness-
// proven counted-vmcnt single-buffer):
//   entry: raw(t)=8 in flight; BAR; stage K/V(t) [4]; vmcnt(4) retires raw(t);
//   COMBINE; issue raw(t+1) [8]; vmcnt(8) retires stages (raw(t+1) stays); BAR; compute.

#define WAITV8 do { asm volatile("s_waitcnt vmcnt(8)" ::: "memory"); } while (0)
#define WAITV4 do { asm volatile("s_waitcnt vmcnt(4)" ::: "memory"); } while (0)
#define WAITV0 do { asm volatile("s_waitcnt vmcnt(0)" ::: "memory"); } while (0)
#define SB0    __builtin_amdgcn_sched_barrier(0)
#define BAR    __builtin_amdgcn_s_barrier()

// lB is LOCAL to this split (bp/mp already include kv0); lB in [0, 960]
#define LOAD_RAW(lB) do {                                                     \
    rb0 = *reinterpret_cast<const f32x4*>(bp + (lB) + g * 4);                 \
    rm0 = *reinterpret_cast<const f32x4*>(mp + (lB) + g * 4);                 \
    rb1 = *reinterpret_cast<const f32x4*>(bp + (lB) + 16 + g * 4);            \
    rm1 = *reinterpret_cast<const f32x4*>(mp + (lB) + 16 + g * 4);            \
    rb2 = *reinterpret_cast<const f32x4*>(bp + (lB) + 32 + g * 4);            \
    rm2 = *reinterpret_cast<const f32x4*>(mp + (lB) + 32 + g * 4);            \
    rb3 = *reinterpret_cast<const f32x4*>(bp + (lB) + 48 + g * 4);            \
    rm3 = *reinterpret_cast<const f32x4*>(mp + (lB) + 48 + g * 4);            \
  } while (0)

#define COMBINE do {                                                          \
    bm0 = (rb0 + rm0) * L2E; bm1 = (rb1 + rm1) * L2E;                         \
    bm2 = (rb2 + rm2) * L2E; bm3 = (rb3 + rm3) * L2E;                         \
  } while (0)

// kvB is GLOBAL (Kp/Vp do not include kv0)
#define STAGE_K(kvB) do {                                                                    \
    load_lds16(Kp + (size_t)((kvB) + w * 16 + srow) * HD + ksrc,     &Ks[(w * 2) * 512]);    \
    load_lds16(Kp + (size_t)((kvB) + w * 16 + 8 + srow) * HD + ksrc, &Ks[(w * 2 + 1) * 512]);\
  } while (0)

#define STAGE_V(kvB) do {                                                                    \
    load_lds16(Vp + (size_t)(w * 16 + srow) * S_LEN + (kvB) + ksrc,     &Vs[(w * 2) * 512]);    \
    load_lds16(Vp + (size_t)(w * 16 + 8 + srow) * S_LEN + (kvB) + ksrc, &Vs[(w * 2 + 1) * 512]);\
  } while (0)

#define BIAS_COL(SCN, BMN) do {                                               \
    SCN[0] = SCN[0] * SC + BMN[0];                                            \
    SCN[1] = SCN[1] * SC + BMN[1];                                            \
    SCN[2] = SCN[2] * SC + BMN[2];                                            \
    SCN[3] = SCN[3] * SC + BMN[3];                                            \
    mt_ = fmaxf(mt_, fmaxf(fmaxf(SCN[0], SCN[1]), fmaxf(SCN[2], SCN[3])));    \
  } while (0)

#define EXP_COL(SCN) do {                                                     \
    SCN[0] = EXP2F(SCN[0] - mn_); SCN[1] = EXP2F(SCN[1] - mn_);               \
    SCN[2] = EXP2F(SCN[2] - mn_); SCN[3] = EXP2F(SCN[3] - mn_);               \
  } while (0)

#define PWR_COL(NN, SCN) do {                                                 \
    u16x4 pk_;                                                                \
    pk_[0] = f2bf(SCN[0]); pk_[1] = f2bf(SCN[1]);                             \
    pk_[2] = f2bf(SCN[2]); pk_[3] = f2bf(SCN[3]);                             \
    const int colb_ = ((NN) * 16 + 4 * g) * 2;                                \
    *reinterpret_cast<u16x4*>(                                                \
        reinterpret_cast<char*>(Pw_) + (q << 7) + (colb_ ^ ((q & 7) << 4))) = pk_; \
  } while (0)

#define COMPUTE_TILE do {                                                     \
    f32x4 sc0_, sc1_, sc2_, sc3_;                                             \
    { bf16x8 a_ = lds_swz_read(Ks, 0 * 16 + q, cbq);                          \
      bf16x8 b_ = lds_swz_read(Ks, 0 * 16 + q, 64 + cbq);                     \
      f32x4 z_ = {}; z_ = mfma16(a_, qf0, z_); sc0_ = mfma16(b_, qf1, z_); }  \
    { bf16x8 a_ = lds_swz_read(Ks, 1 * 16 + q, cbq);                          \
      bf16x8 b_ = lds_swz_read(Ks, 1 * 16 + q, 64 + cbq);                     \
      f32x4 z_ = {}; z_ = mfma16(a_, qf0, z_); sc1_ = mfma16(b_, qf1, z_); }  \
    { bf16x8 a_ = lds_swz_read(Ks, 2 * 16 + q, cbq);                          \
      bf16x8 b_ = lds_swz_read(Ks, 2 * 16 + q, 64 + cbq);                     \
      f32x4 z_ = {}; z_ = mfma16(a_, qf0, z_); sc2_ = mfma16(b_, qf1, z_); }  \
    { bf16x8 a_ = lds_swz_read(Ks, 3 * 16 + q, cbq);                          \
      bf16x8 b_ = lds_swz_read(Ks, 3 * 16 + q, 64 + cbq);                     \
      f32x4 z_ = {}; z_ = mfma16(a_, qf0, z_); sc3_ = mfma16(b_, qf1, z_); }  \
    float mt_ = -3.0e38f;                                                     \
    BIAS_COL(sc0_, bm0); BIAS_COL(sc1_, bm1);                                 \
    BIAS_COL(sc2_, bm2); BIAS_COL(sc3_, bm3);                                 \
    mt_ = fmaxf(mt_, __shfl_xor(mt_, 16));                                    \
    mt_ = fmaxf(mt_, __shfl_xor(mt_, 32));                                    \
    const float mn_ = fmaxf(m_run, mt_);                                      \
    const float corr_ = EXP2F(m_run - mn_);                                   \
    m_run = mn_;                                                              \
    EXP_COL(sc0_); EXP_COL(sc1_); EXP_COL(sc2_); EXP_COL(sc3_);               \
    f32x4 ls4_ = sc0_ + sc1_ + sc2_ + sc3_;                                   \
    float ls_ = ls4_[0] + ls4_[1] + ls4_[2] + ls4_[3];                        \
    ls_ += __shfl_xor(ls_, 16);                                               \
    ls_ += __shfl_xor(ls_, 32);                                               \
    l_run = l_run * corr_ + ls_;                                              \
    acc0_ *= corr_; acc1_ *= corr_; acc2_ *= corr_; acc3_ *= corr_;           \
    PWR_COL(0, sc0_); PWR_COL(1, sc1_); PWR_COL(2, sc2_); PWR_COL(3, sc3_);   \
    bf16x8 pf0_ = lds_swz_read(Pw_, q, cbq);                                  \
    bf16x8 pf1_ = lds_swz_read(Pw_, q, 64 + cbq);                             \
    { bf16x8 a_ = lds_swz_read(Vs, 0 * 16 + q, cbq);                          \
      bf16x8 b_ = lds_swz_read(Vs, 0 * 16 + q, 64 + cbq);                     \
      acc0_ = mfma16(a_, pf0_, acc0_); acc0_ = mfma16(b_, pf1_, acc0_); }     \
    { bf16x8 a_ = lds_swz_read(Vs, 1 * 16 + q, cbq);                          \
      bf16x8 b_ = lds_swz_read(Vs, 1 * 16 + q, 64 + cbq);                     \
      acc1_ = mfma16(a_, pf0_, acc1_); acc1_ = mfma16(b_, pf1_, acc1_); }     \
    { bf16x8 a_ = lds_swz_read(Vs, 2 * 16 + q, cbq);                          \
      bf16x8 b_ = lds_swz_read(Vs, 2 * 16 + q, 64 + cbq);                     \
      acc2_ = mfma16(a_, pf0_, acc2_); acc2_ = mfma16(b_, pf1_, acc2_); }     \
    { bf16x8 a_ = lds_swz_read(Vs, 3 * 16 + q, cbq);                          \
      bf16x8 b_ = lds_swz_read(Vs, 3 * 16 + q, 64 + cbq);                     \
      acc3_ = mfma16(a_, pf0_, acc3_); acc3_ = mfma16(b_, pf1_, acc3_); }     \
  } while (0)

__global__ __launch_bounds__(256) __attribute__((amdgpu_waves_per_eu(4, 5)))
void attn_kernel(const unsigned short* __restrict__ Q,
                 const unsigned short* __restrict__ Kmat,
                 const unsigned short* __restrict__ Vt,
                 const float* __restrict__ rel_bias,
                 const float* __restrict__ mask,
                 unsigned short* __restrict__ ctxp0,
                 unsigned short* __restrict__ ctxp1,
                 float* __restrict__ Mbuf,
                 float* __restrict__ Lbuf)
{
  __shared__ unsigned short Ks[64 * 64];
  __shared__ unsigned short Vs[64 * 64];
  __shared__ unsigned short Ps[4][16 * 64];

  // XCD-chunked bijective remap: 2048 = 8 XCDs x 256; (s, b) fastest so blocks sharing
  // bias rows land on the same XCD.
  const int logical = (blockIdx.x & 7) * 256 + (blockIdx.x >> 3);
  const int s  = logical & 1;          // K-split
  const int b  = (logical >> 1) & 1;
  const int qt = (logical >> 2) & 31;
  const int h  = logical >> 7;

  const int lane = threadIdx.x & 63, w = threadIdx.x >> 6;
  const int q = lane & 15, g = lane >> 4;
  const int bh = b * NH + h;
  const int qRow = qt * 64 + w * 16;
  const int kv0 = s << 10;             // this split's k base (global elements)
  const unsigned short* Qp = Q + ((size_t)bh * S_LEN + qRow) * HD;
  bf16x8 qf0 = *reinterpret_cast<const bf16x8*>(Qp + (size_t)q * HD + g * 8);
  bf16x8 qf1 = *reinterpret_cast<const bf16x8*>(Qp + (size_t)q * HD + 32 + g * 8);

  const unsigned short* Kp = Kmat + (size_t)bh * S_LEN * HD;
  const unsigned short* Vp = Vt + (size_t)bh * HD * S_LEN;
  const float* bp = rel_bias + (size_t)h * S_LEN * S_LEN + (size_t)(qRow + q) * S_LEN + kv0;
  const float* mp = mask + (size_t)(qRow + q) * S_LEN + kv0;

  float m_run = -3.0e38f, l_run = 0.f;
  f32x4 acc0_ = {}, acc1_ = {}, acc2_ = {}, acc3_ = {};
  f32x4 rb0, rb1, rb2, rb3, rm0, rm1, rm2, rm3;
  f32x4 bm0, bm1, bm2, bm3;

  const float SC  = 0.125f * 1.44269504089f;  // head scale * log2(e)
  const float L2E = 1.44269504089f;

  const int srow = lane >> 3;
  const int ksrc = ((lane & 7) ^ srow) * 8;   // pre-swizzled global k-offset
  const int cbq = g << 4;
  unsigned short* Pw_ = Ps[w];

  // prologue: raw(0) in flight (8) -- loop entry invariant
  LOAD_RAW(0);
  SB0;

  for (int t = 0; t < 15; ++t) {
    const int kvB = kv0 + t * 64;      // global
    BAR;                               // all waves done reading Ks/Vs of t-1
    STAGE_K(kvB); STAGE_V(kvB);        // in-flight: raw(t)8 + stage4
    SB0;
    WAITV4; SB0;                       // retire raw(t); stages remain
    COMBINE;                           // bm <- raw(t)
    LOAD_RAW((t + 1) * 64);            // raw(t+1), LOCAL offset
    SB0;
    WAITV8; SB0;                       // retire stages; raw(t+1) stays in flight
    BAR;                               // stages visible to all waves
    COMPUTE_TILE;
  }
  // tail t = 15
  {
    const int kvB = kv0 + 15 * 64;
    BAR;
    STAGE_K(kvB); STAGE_V(kvB);
    SB0;
    WAITV4; SB0;
    COMBINE;
    WAITV0; SB0;
    BAR;
    COMPUTE_TILE;
  }

  // epilogue: normalize, redistribute through per-wave LDS, write split partial
  const float inv = 1.0f / l_run;
  acc0_ *= inv; acc1_ *= inv; acc2_ *= inv; acc3_ *= inv;
  PWR_COL(0, acc0_); PWR_COL(1, acc1_); PWR_COL(2, acc2_); PWR_COL(3, acc3_);
  bf16x8 c0 = lds_swz_read(Pw_, q, g << 4);
  bf16x8 c1 = lds_swz_read(Pw_, q, 64 + (g << 4));
  unsigned short* cp = (s ? ctxp1 : ctxp0) +
                       ((size_t)(b * S_LEN + qRow + q)) * DM + h * HD;
  *reinterpret_cast<bf16x8*>(cp + 8 * g) = c0;
  *reinterpret_cast<bf16x8*>(cp + 32 + 8 * g) = c1;
  if (g == 0) {
    const int mlIdx = (s << 16) + (bh << 11) + qRow + q;
    Mbuf[mlIdx] = m_run;
    Lbuf[mlIdx] = l_run;
  }
}

// ---------------- merge: combine the two K-split partials ----------------
__global__ void merge_kernel(const unsigned short* __restrict__ ctxp0,
                             const unsigned short* __restrict__ ctxp1,
                             const float* __restrict__ Mbuf,
                             const float* __restrict__ Lbuf,
                             unsigned short* __restrict__ ctx){
  const long e = ((long)blockIdx.x * 256 + threadIdx.x) * 4;  // elem in [B*S*DM = 4M]
  const int b = (int)(e >> 21);
  const int srow = (int)((e >> 10) & 2047);
  const int d = (int)(e & 1023);
  const int h = d >> 6;
  const int idx = ((b * NH + h) << 11) + srow;
  const float m0 = Mbuf[idx],  m1 = Mbuf[(1 << 16) + idx];
  const float l0 = Lbuf[idx],  l1 = Lbuf[(1 << 16) + idx];
  const float mm = fmaxf(m0, m1);
  const float w0 = EXP2F(m0 - mm) * l0;
  const float w1 = EXP2F(m1 - mm) * l1;
  const float inv = 1.0f / (w0 + w1);
  u16x4 c0 = *reinterpret_cast<const u16x4*>(ctxp0 + e);
  u16x4 c1 = *reinterpret_cast<const u16x4*>(ctxp1 + e);
  u16x4 o;
  #pragma unroll
  for (int j = 0; j < 4; ++j)
    o[j] = f2bf((bf2f(c0[j]) * w0 + bf2f(c1[j]) * w1) * inv);
  *reinterpret_cast<u16x4*>(ctx + e) = o;
}

extern "C" void kernel_launch(void* const* d_in, const int* in_sizes, int n_in,
                              void* d_out, int out_size, void* d_ws, size_t ws_size,
                              hipStream_t stream) {
  (void)in_sizes; (void)n_in; (void)out_size; (void)ws_size;
  const float* x  = (const float*)d_in[0];
  const float* rb = (const float*)d_in[1];
  const float* mk = (const float*)d_in[2];
  const float* Wq = (const float*)d_in[3];
  const float* bq = (const float*)d_in[4];
  const float* Wk = (const float*)d_in[5];
  const float* bk = (const float*)d_in[6];
  const float* Wv = (const float*)d_in[7];
  const float* bv = (const float*)d_in[8];
  const float* Wo = (const float*)d_in[9];
  const float* bo = (const float*)d_in[10];
  float* out = (float*)d_out;

  // ws layout (unsigned short elems), 24M total = 48MB (same as passing rounds):
  //  [0,4M)    xb      (QKV GEMM input; DEAD after gemm<0> -> reused as split-1 partial)
  //  [4M,5M)   wqb     (DEAD after gemm<0> -> reused as Mbuf/Lbuf)
  //  [5M,6M)   wkb     [6M,7M) wvb    [7M,8M) wob (live until gemm<1>)
  //  [8M,12M)  Qw   [12M,16M) Kw   [16M,20M) Vtw
  //  [20M,24M) ctx  (split-0 partial, then merged in place)
  unsigned short* ws  = (unsigned short*)d_ws;
  unsigned short* xb  = ws;
  unsigned short* wqb = ws + (1L << 22);
  unsigned short* wkb = wqb + (1L << 20);
  unsigned short* wvb = wkb + (1L << 20);
  unsigned short* wob = wvb + (1L << 20);
  unsigned short* Qw  = wob + (1L << 20);
  unsigned short* Kw  = Qw + (1L << 22);
  unsigned short* Vtw = Kw + (1L << 22);
  unsigned short* ctx = Vtw + (1L << 22);
  unsigned short* ctxp1 = xb;                 // split-1 partial reuses xb
  float* Mb = (float*)wqb;                    // 2^17 f32 = 512KB
  float* Lb = (float*)(wqb + (1L << 19));     // next 512KB, inside wqb's 2MB

  prep_kernel<<<8192, 256, 0, stream>>>(x, Wq, Wk, Wv, Wo, ws);
  gemm_bt_kernel<0><<<dim3(24, 32), 256, 0, stream>>>(
      xb, wqb, wkb, wvb, bq, bk, bv, Qw, Kw, Vtw, nullptr);
  attn_kernel<<<2048, 256, 0, stream>>>(Qw, Kw, Vtw, rb, mk, ctx, ctxp1, Mb, Lb);
  merge_kernel<<<4096, 256, 0, stream>>>(ctx, ctxp1, Mb, Lb, ctx);
  gemm_bt_kernel<1><<<dim3(8, 32), 256, 0, stream>>>(
      ctx, wob, nullptr, nullptr, bo, nullptr, nullptr, nullptr, nullptr, nullptr, out);
}